// Round 1
// baseline (761.757 us; speedup 1.0000x reference)
//
#include <hip/hip_runtime.h>

#define B_ 256
#define T_ 500
#define N_ 256
// plane sizes
#define BN_ 65536            // B_*N_
#define STP_ 196608          // 3*B_*N_ (states per-t stride)

// ---------------------------------------------------------------------------
// W1t[k][n] = W1[n][k]  (256x256 fp32)
// ---------------------------------------------------------------------------
__global__ __launch_bounds__(256)
void w1_transpose_kernel(const float* __restrict__ W1, float* __restrict__ W1t) {
    __shared__ float tile[32][33];
    const int bx = blockIdx.x & 7;
    const int by = blockIdx.x >> 3;
    const int tx = threadIdx.x & 31;
    const int ty = threadIdx.x >> 5;  // 0..7
#pragma unroll
    for (int i = 0; i < 4; ++i)
        tile[ty + 8 * i][tx] = W1[(by * 32 + ty + 8 * i) * 256 + bx * 32 + tx];
    __syncthreads();
#pragma unroll
    for (int i = 0; i < 4; ++i)
        W1t[(bx * 32 + ty + 8 * i) * 256 + by * 32 + tx] = tile[tx][ty + 8 * i];
}

// ---------------------------------------------------------------------------
// I = X @ W1^T, fp32.  X viewed [B*T, 256]; output scattered into the v-plane
// of states: states[(t*3+0)*B*N + b*N + n].
// 64x64 tile, BK=64, 256 threads, 4x4 microtile, double-buffered LDS.
// grid = (B*8, 4): blockIdx.x -> (b, t-tile), blockIdx.y -> n-tile.
// ---------------------------------------------------------------------------
__global__ __launch_bounds__(256)
void gemm_kernel(const float* __restrict__ X, const float* __restrict__ W1t,
                 float* __restrict__ states) {
    __shared__ float As[2][64 * 68];   // [m][k], pad 68 -> 2-way (free) conflicts
    __shared__ float Bs[2][64 * 64];   // [k][n], conflict-free reads

    const int tid   = threadIdx.x;
    const int bb    = blockIdx.x >> 3;        // batch
    const int tt    = blockIdx.x & 7;         // t-tile within batch
    const int n0    = blockIdx.y << 6;
    const int trow0 = tt << 6;
    const int valid = min(64, T_ - trow0);    // last tile has 52 valid rows

    const float* Ab = X + ((size_t)bb * T_ + trow0) * 256;

    const int lr  = tid >> 4;          // 0..15 (staging row)
    const int lc4 = (tid & 15) << 2;   // 0..60 (staging col*4)

    float4 ra[4], rb[4];
#pragma unroll
    for (int i = 0; i < 4; ++i) {                 // prologue: chunk 0
        const int r  = lr + (i << 4);
        const int rc = min(r, valid - 1);         // clamp OOB rows (recompute row)
        ra[i] = *(const float4*)(Ab + (size_t)rc * 256 + lc4);
        rb[i] = *(const float4*)(W1t + (size_t)r * 256 + n0 + lc4);
    }

    float acc[4][4];
#pragma unroll
    for (int i = 0; i < 4; ++i)
#pragma unroll
        for (int j = 0; j < 4; ++j) acc[i][j] = 0.f;

    const int tm4 = (tid >> 4) << 2;
    const int tn4 = (tid & 15) << 2;

    for (int c = 0; c < 4; ++c) {
        const int cur = c & 1;
#pragma unroll
        for (int i = 0; i < 4; ++i) {             // regs -> LDS
            const int r = lr + (i << 4);
            *(float4*)&As[cur][r * 68 + lc4] = ra[i];
            *(float4*)&Bs[cur][r * 64 + lc4] = rb[i];
        }
        __syncthreads();
        if (c < 3) {                              // prefetch next chunk (hidden under FMAs)
            const int kc = (c + 1) << 6;
#pragma unroll
            for (int i = 0; i < 4; ++i) {
                const int r  = lr + (i << 4);
                const int rc = min(r, valid - 1);
                ra[i] = *(const float4*)(Ab + (size_t)rc * 256 + kc + lc4);
                rb[i] = *(const float4*)(W1t + (size_t)(kc + r) * 256 + n0 + lc4);
            }
        }
#pragma unroll
        for (int kk = 0; kk < 64; kk += 4) {
            float4 av[4], bv[4];
#pragma unroll
            for (int i = 0; i < 4; ++i)
                av[i] = *(const float4*)&As[cur][(tm4 + i) * 68 + kk];
#pragma unroll
            for (int j = 0; j < 4; ++j)
                bv[j] = *(const float4*)&Bs[cur][(kk + j) * 64 + tn4];
#pragma unroll
            for (int e = 0; e < 4; ++e) {
                const float* bp = (const float*)&bv[e];
#pragma unroll
                for (int i = 0; i < 4; ++i) {
                    const float ae = ((const float*)&av[i])[e];
                    acc[i][0] += ae * bp[0];
                    acc[i][1] += ae * bp[1];
                    acc[i][2] += ae * bp[2];
                    acc[i][3] += ae * bp[3];
                }
            }
        }
        __syncthreads();
    }

#pragma unroll
    for (int i = 0; i < 4; ++i) {
        const int r = tm4 + i;
        if (r < valid) {
            const size_t t = (size_t)(trow0 + r);
            float4 o;
            o.x = acc[i][0]; o.y = acc[i][1]; o.z = acc[i][2]; o.w = acc[i][3];
            *(float4*)&states[t * STP_ + (size_t)bb * 256 + n0 + tn4] = o;
        }
    }
}

// ---------------------------------------------------------------------------
// Sequential Izhikevich scan. One block per batch element b, one thread per
// neuron n. v,u live in registers across all 500 steps; li via block reduce.
// I[t] is read from the states v-plane (written there by gemm_kernel) and
// overwritten in place by v_new — same thread, read-before-write.
// ---------------------------------------------------------------------------
__global__ __launch_bounds__(256)
void scan_kernel(float* __restrict__ states, float* __restrict__ out_s,
                 float* __restrict__ out_dec,
                 const float* __restrict__ st_snn, const float* __restrict__ st_li,
                 const float* __restrict__ W2,
                 const float* __restrict__ pa, const float* __restrict__ pb,
                 const float* __restrict__ pc, const float* __restrict__ pd,
                 const float* __restrict__ pv0, const float* __restrict__ pv1,
                 const float* __restrict__ pv2, const float* __restrict__ ptau,
                 const float* __restrict__ pth, const float* __restrict__ pleak) {
    const int bb   = blockIdx.x;
    const int tid  = threadIdx.x;
    const int boff = bb * 256 + tid;

    float v  = st_snn[boff];
    float u  = st_snn[BN_ + boff];
    float li = st_li[bb];                        // only thread 0's copy is used

    const float a_   = pa[tid];
    const float b_   = pb[tid];
    const float c_   = pc[tid];
    const float d_   = pd[tid];
    const float v0_  = pv0[tid];
    const float v1_  = pv1[tid];
    const float v2_  = pv2[tid];
    const float coef = (1.0f / ptau[tid]) * a_;  // (DT/tau_u)*a, DT=1
    const float th_  = pth[tid];
    const float w2_  = W2[tid];
    const float lk_  = pleak[0];
    const float olk_ = 1.0f - lk_;

    __shared__ float red[2][4];

    float Icur = states[boff];                   // t=0 I value
    for (int t = 0; t < T_; ++t) {
        const size_t pbase = (size_t)t * STP_ + boff;
        float Inext = 0.f;
        if (t + 1 < T_) Inext = states[pbase + STP_];   // prefetch next I

        // membrane / recovery update (mirror reference op order)
        const float vm = v + (((v2_ * v * v + v1_ * v) + v0_ - u) + Icur);
        const float um = u + coef * (b_ * v - u);
        const bool  sp = (vm - th_) > 0.f;
        const float s  = sp ? 1.f : 0.f;
        v = sp ? c_ : vm;           // == vm*(1-s)+s*c exactly for s in {0,1}
        u = sp ? (um + d_) : um;    // == um + s*d

        states[pbase]           = v;   // overwrite consumed I with v_new
        states[pbase + BN_]     = u;
        states[pbase + 2 * BN_] = s;
        out_s[(size_t)t * BN_ + boff] = s;

        // li readout: block reduce of s*W2[n]
        float ds = s * w2_;
#pragma unroll
        for (int off = 32; off; off >>= 1) ds += __shfl_xor(ds, off);
        if ((tid & 63) == 0) red[t & 1][tid >> 6] = ds;
        __syncthreads();
        if (tid == 0) {
            const float* rp = red[t & 1];
            const float dot = (rp[0] + rp[1]) + (rp[2] + rp[3]);
            li = lk_ * li + olk_ * dot;
            out_dec[(size_t)t * 256 + bb] = li;
        }
        Icur = Inext;
    }
}

// ---------------------------------------------------------------------------
extern "C" void kernel_launch(void* const* d_in, const int* in_sizes, int n_in,
                              void* d_out, int out_size, void* d_ws, size_t ws_size,
                              hipStream_t stream) {
    const float* input  = (const float*)d_in[0];   // [B,T,N]
    const float* st_snn = (const float*)d_in[1];   // [3,B,N]
    const float* st_li  = (const float*)d_in[2];   // [B,1]
    const float* W1     = (const float*)d_in[3];   // [N,N]
    const float* W2     = (const float*)d_in[4];   // [1,N]
    const float* pa     = (const float*)d_in[5];
    const float* pb     = (const float*)d_in[6];
    const float* pc     = (const float*)d_in[7];
    const float* pd     = (const float*)d_in[8];
    const float* pv0    = (const float*)d_in[9];
    const float* pv1    = (const float*)d_in[10];
    const float* pv2    = (const float*)d_in[11];
    const float* ptau   = (const float*)d_in[12];
    const float* pth    = (const float*)d_in[13];
    const float* pleak  = (const float*)d_in[14];

    float* out        = (float*)d_out;
    float* out_s      = out;                                 // [500,256,256]
    float* out_states = out + (size_t)T_ * BN_;              // [500,3,256,256]
    float* out_dec    = out + (size_t)T_ * BN_ + (size_t)T_ * STP_; // [500,256]

    // W1^T scratch lives in the decoded region (256KB of 512KB); the scan
    // kernel fully overwrites it afterwards. No dependence on ws_size.
    float* W1t = out_dec;

    w1_transpose_kernel<<<dim3(64), dim3(256), 0, stream>>>(W1, W1t);
    gemm_kernel<<<dim3(B_ * 8, 4), dim3(256), 0, stream>>>(input, W1t, out_states);
    scan_kernel<<<dim3(B_), dim3(256), 0, stream>>>(
        out_states, out_s, out_dec, st_snn, st_li, W2,
        pa, pb, pc, pd, pv0, pv1, pv2, ptau, pth, pleak);
}